// Round 7
// baseline (102.813 us; speedup 1.0000x reference)
//
#include <hip/hip_runtime.h>
#include <hip/hip_bf16.h>

// Problem constants (from reference)
#define NN    4096
#define DD    256
#define HH    4
#define DHH   64
#define EDGES 131072
#define CAP   128           // per-row neighbor capacity; deg ~ Poisson(32), P(>128) < 1e-40
#define RPB   2             // rows per attn block (1 wave per row)
#define LRELU_ALPHA 0.2f

typedef __hip_bfloat16 bf16;
typedef __attribute__((ext_vector_type(8))) short short8v;   // 8 bf16 = 4 VGPR
typedef __attribute__((ext_vector_type(4))) float f32x4;     // MFMA acc

// Round-12: OCCUPANCY. R6 rocprof (first direct hproj measurement): 55.7us,
// HBM 2.3%, MfmaUtil 1%, VALUBusy 6%, Occupancy 10% -- latency-bound at
// 1 wave/SIMD (256 blocks x 4 waves on 256 CUs), ~256 dependent 4B W-loads
// per thread against a cold L2 (the 256MiB ws re-poison flushes L2+L3 every
// iteration). Session ladder: 4 waves/CU -> 55-75us; 8-16 waves/CU -> 38-45us.
// Fix: split the q (N-subtile) loop ACROSS waves: block = 16-row M-tile x
// 16 waves (wave = head*4 + q), 1024 threads, grid 256 -> 16 waves/CU
// (4/SIMD), and each wave holds ONE f32x4 acc -> more VGPRs free for load
// pipelining. Per-q MFMA chain unchanged -> hb BIT-IDENTICAL to R6.
// esrc/edst: per-q 16-lane shfl reduce (same tree) then q-ascending LDS sum
// -- ~1ulp fp32 reassociation on logits, invisible through softmax.
//
// Split-bf16 MFMA (unchanged): x=xh+xl, w=wh+wl; h = xh*wh + xh*wl + xl*wh
// (fp32 acc); dropped xl*wl ~1e-5, ~400x below hb's bf16 ulp. C/D mapping
// col=lane&15, row=4*(lane>>4)+reg (HW-verified); A/B k-slot bijection cancels.
//
// ws layout, 4.2 MB total:
//   hb    [N][H][DH]   bf16  @ 0         (2 MB)
//   esrc  [N][H]       f32   @ 2097152   (64 KB)
//   edst  [N][H]       f32   @ 2162688   (64 KB)
//   bmg   [N][N/32]    u32   @ 2228224   (2 MB)   <- hipMemsetAsync node
//
// Harness floor per iteration: 256 MiB 0xAA ws re-poison fill ~43us + ~20us
// tiny input-restore dispatches. Untouchable.

__device__ __forceinline__ float bf_lo(unsigned int u) { return __uint_as_float(u << 16); }
__device__ __forceinline__ float bf_hi(unsigned int u) { return __uint_as_float(u & 0xffff0000u); }

__device__ __forceinline__ unsigned short f2bf_rne(float f) {
    unsigned int u = __float_as_uint(f);
    return (unsigned short)((u + 0x7fffu + ((u >> 16) & 1u)) >> 16);   // RNE; no NaN here
}
__device__ __forceinline__ float bf2f(unsigned short s) {
    return __uint_as_float(((unsigned int)s) << 16);
}

// ---------------------------------------------------------------------------
// Kernel A (fused): MFMA hproj, 16 rows/block x 16 waves + 512-edge slice.
//   grid = 256 blocks x 1024 threads. wave wv = (head = wv>>2, q = wv&3):
//   one 16x16 C-tile per wave (cols head*64+q*16..+15), 8 K-steps of 32,
//   3 split MFMAs each = 24 MFMA/wave. 16 waves/CU = 4/SIMD latency hiding.
//   Edge phase (1 edge/thread for t<512, fire-and-forget atomicOr).
//   esrc/edst: per-wave 16-lane shfl reduce -> LDS -> q-ascending final sum.
// ---------------------------------------------------------------------------
__global__ __launch_bounds__(1024) void hproj_edges_kernel(
    const float* __restrict__ x, const float* __restrict__ W,
    const float* __restrict__ a_src, const float* __restrict__ a_dst,
    const int* __restrict__ ei, const float* __restrict__ ev,
    bf16* __restrict__ hb, float* __restrict__ esrc, float* __restrict__ edst,
    unsigned int* __restrict__ bmg)
{
    __shared__ float pvs[16][16];   // [wave][row-in-tile] partial esrc
    __shared__ float pvd[16][16];   // [wave][row-in-tile] partial edst

    const int t  = threadIdx.x;
    const int i0 = blockIdx.x * 16;

    // edge slice: 512 edges/block, 1 per thread for t<512, fire-and-forget OR
    if (t < 512) {
        const int   e  = blockIdx.x * 512 + t;
        const float vv = ev[e];
        const int   er = ei[e];            // edge_index[0][e]
        const int   ec = ei[EDGES + e];    // edge_index[1][e]
        if (vv > 0.f)
            atomicOr(&bmg[er * (NN / 32) + (ec >> 5)], 1u << (ec & 31));
    }

    const int wv   = t >> 6;        // 0..15
    const int h    = wv >> 2;       // head
    const int q    = wv & 3;        // N-subtile within head
    const int lane = t & 63;
    const int mrow = lane & 15;     // A row / C col index
    const int kgrp = lane >> 4;     // k-group / C row group

    const float* xp = x + (size_t)(i0 + mrow) * DD + 8 * kgrp;
    // element (ks,e) of this lane's B fragment: Wb[(ks*32 + 8*kgrp + e)*DHH]
    const float* Wb = W + (size_t)h * (DD * DHH) + q * 16 + mrow;

    f32x4 acc = (f32x4){0.f, 0.f, 0.f, 0.f};

    #pragma unroll
    for (int ks = 0; ks < 8; ++ks) {
        // A fragment: x split hi/lo on the fly
        const float4 u0 = *(const float4*)(xp + ks * 32);
        const float4 u1 = *(const float4*)(xp + ks * 32 + 4);
        const float v[8] = {u0.x, u0.y, u0.z, u0.w, u1.x, u1.y, u1.z, u1.w};
        short8v ah, al;
        #pragma unroll
        for (int e = 0; e < 8; ++e) {
            const unsigned short hi = f2bf_rne(v[e]);
            ah[e] = (short)hi;
            al[e] = (short)f2bf_rne(v[e] - bf2f(hi));
        }
        // B fragment inline from fp32 W (same values/order as R6 -> acc bit-identical)
        const float* wk = Wb + (size_t)(ks * 32 + 8 * kgrp) * DHH;
        short8v bh, bl;
        #pragma unroll
        for (int e = 0; e < 8; ++e) {
            const float we = wk[(size_t)e * DHH];
            const unsigned short hi = f2bf_rne(we);
            bh[e] = (short)hi;
            bl[e] = (short)f2bf_rne(we - bf2f(hi));
        }
        acc = __builtin_amdgcn_mfma_f32_16x16x32_bf16(ah, bh, acc, 0, 0, 0);
        acc = __builtin_amdgcn_mfma_f32_16x16x32_bf16(ah, bl, acc, 0, 0, 0);
        acc = __builtin_amdgcn_mfma_f32_16x16x32_bf16(al, bh, acc, 0, 0, 0);
    }

    // hb store: C/D mapping col=mrow (within this q-tile), row=4*kgrp+reg
    {
        const int col = h * 64 + q * 16 + mrow;
        #pragma unroll
        for (int reg = 0; reg < 4; ++reg) {
            const int row = i0 + 4 * kgrp + reg;
            hb[(size_t)row * (HH * DHH) + col] = __float2bfloat16(acc[reg]);
        }
    }

    // esrc/edst partials: dot over this wave's 16 dh, 16-lane shfl tree
    {
        const float as = a_src[h * DHH + q * 16 + mrow];
        const float ad = a_dst[h * DHH + q * 16 + mrow];
        float vs[4], vd[4];
        #pragma unroll
        for (int reg = 0; reg < 4; ++reg) {
            vs[reg] = acc[reg] * as;
            vd[reg] = acc[reg] * ad;
        }
        #pragma unroll
        for (int reg = 0; reg < 4; ++reg) {
            #pragma unroll
            for (int off = 1; off < 16; off <<= 1) {
                vs[reg] += __shfl_xor(vs[reg], off, 64);
                vd[reg] += __shfl_xor(vd[reg], off, 64);
            }
        }
        if (mrow == 0) {
            #pragma unroll
            for (int reg = 0; reg < 4; ++reg) {
                pvs[wv][4 * kgrp + reg] = vs[reg];
                pvd[wv][4 * kgrp + reg] = vd[reg];
            }
        }
    }
    __syncthreads();

    // final reduce: q-ascending deterministic sum, one head per q==0 wave
    if (q == 0 && lane < 16) {
        float s = 0.f, d = 0.f;
        #pragma unroll
        for (int qq = 0; qq < 4; ++qq) {
            s += pvs[h * 4 + qq][lane];
            d += pvd[h * 4 + qq][lane];
        }
        esrc[(i0 + lane) * HH + h] = s;
        edst[(i0 + lane) * HH + h] = d;
    }
}

// ---------------------------------------------------------------------------
// Kernel B: 2 rows/block, 1 wave/row, 128 threads, grid = NN/2 = 2048.
// [unchanged]
// ---------------------------------------------------------------------------
__global__ __launch_bounds__(128) void attn_kernel(
    const unsigned int* __restrict__ bmg, const bf16* __restrict__ hb,
    const float* __restrict__ esrc, const float* __restrict__ edst,
    float* __restrict__ out)
{
    __shared__ int nbr[RPB][CAP];
    __shared__ __align__(16) float wts[RPB][CAP][HH];   // [row][k][head]

    const int t = threadIdx.x;
    const int r = t >> 6, lane = t & 63;
    const int i = blockIdx.x * RPB + r;

    // ---- bitmask -> compact neighbor list (wave-parallel, no atomics) ----
    const uint2 wp = *(const uint2*)(bmg + (size_t)i * (NN / 32) + 2 * lane);
    const int c = __popc(wp.x) + __popc(wp.y);
    int inc = c;
    #pragma unroll
    for (int off = 1; off < 64; off <<= 1) {
        const int nn = __shfl_up(inc, off, 64);
        if (lane >= off) inc += nn;
    }
    int p = inc - c;
    const int deg = min(__shfl(inc, 63, 64), CAP);
    unsigned int w = wp.x;
    while (w) { const int b = __ffs(w) - 1; w &= w - 1; if (p < CAP) nbr[r][p] = (lane << 6) + b; ++p; }
    w = wp.y;
    while (w) { const int b = __ffs(w) - 1; w &= w - 1; if (p < CAP) nbr[r][p] = (lane << 6) + 32 + b; ++p; }
    __syncthreads();

    const int head = lane >> 4;          // lane covers dims [4*lane, 4*lane+3]
    float4 acc = make_float4(0.f, 0.f, 0.f, 0.f);
    float4 sm  = make_float4(0.f, 0.f, 0.f, 0.f);

    if (deg > 0) {
        const float4 es4 = *(const float4*)(esrc + (size_t)i * HH);
        float4 mx = make_float4(-INFINITY, -INFINITY, -INFINITY, -INFINITY);
        // pass 1: logits (all 4 heads per lane), track max
        for (int k = lane; k < deg; k += 64) {
            const float4 ed = *(const float4*)(edst + (size_t)nbr[r][k] * HH);
            float4 e4;
            e4.x = es4.x + ed.x; e4.x = e4.x > 0.f ? e4.x : LRELU_ALPHA * e4.x;
            e4.y = es4.y + ed.y; e4.y = e4.y > 0.f ? e4.y : LRELU_ALPHA * e4.y;
            e4.z = es4.z + ed.z; e4.z = e4.z > 0.f ? e4.z : LRELU_ALPHA * e4.z;
            e4.w = es4.w + ed.w; e4.w = e4.w > 0.f ? e4.w : LRELU_ALPHA * e4.w;
            *(float4*)&wts[r][k][0] = e4;
            mx.x = fmaxf(mx.x, e4.x); mx.y = fmaxf(mx.y, e4.y);
            mx.z = fmaxf(mx.z, e4.z); mx.w = fmaxf(mx.w, e4.w);
        }
        #pragma unroll
        for (int off = 32; off; off >>= 1) {
            mx.x = fmaxf(mx.x, __shfl_xor(mx.x, off, 64));
            mx.y = fmaxf(mx.y, __shfl_xor(mx.y, off, 64));
            mx.z = fmaxf(mx.z, __shfl_xor(mx.z, off, 64));
            mx.w = fmaxf(mx.w, __shfl_xor(mx.w, off, 64));
        }
        // pass 2: exponentiate in place, track sum
        for (int k = lane; k < deg; k += 64) {
            float4 e4 = *(const float4*)&wts[r][k][0];
            e4.x = expf(e4.x - mx.x); e4.y = expf(e4.y - mx.y);
            e4.z = expf(e4.z - mx.z); e4.w = expf(e4.w - mx.w);
            *(float4*)&wts[r][k][0] = e4;
            sm.x += e4.x; sm.y += e4.y; sm.z += e4.z; sm.w += e4.w;
        }
        #pragma unroll
        for (int off = 32; off; off >>= 1) {
            sm.x += __shfl_xor(sm.x, off, 64);
            sm.y += __shfl_xor(sm.y, off, 64);
            sm.z += __shfl_xor(sm.z, off, 64);
            sm.w += __shfl_xor(sm.w, off, 64);
        }
    }
    __syncthreads();   // wts visible across lanes (uniform barrier count per block)

    float inv;
    if (deg == 0) {
        // uniform attention over all N columns: out = mean of h
        const uint2* hp = (const uint2*)hb + lane;   // row j = 64 uint2's
        for (int j = 0; j < NN; ++j) {
            const uint2 u = hp[(size_t)j * 64];
            acc.x += bf_lo(u.x); acc.y += bf_hi(u.x);
            acc.z += bf_lo(u.y); acc.w += bf_hi(u.y);
        }
        inv = 1.f / NN;
    } else {
        // pass 3: acc_d = sum_k w[head][k] * h[j_k][d]; 4 gathers in flight
        const uint2* hp = (const uint2*)hb;
        int k = 0;
        for (; k + 3 < deg; k += 4) {
            const int j0 = nbr[r][k],     j1 = nbr[r][k + 1];
            const int j2 = nbr[r][k + 2], j3 = nbr[r][k + 3];
            const uint2 u0 = hp[(size_t)j0 * 64 + lane];
            const uint2 u1 = hp[(size_t)j1 * 64 + lane];
            const uint2 u2 = hp[(size_t)j2 * 64 + lane];
            const uint2 u3 = hp[(size_t)j3 * 64 + lane];
            const float w0 = wts[r][k][head],     w1 = wts[r][k + 1][head];
            const float w2 = wts[r][k + 2][head], w3 = wts[r][k + 3][head];
            acc.x = fmaf(w0, bf_lo(u0.x), acc.x); acc.y = fmaf(w0, bf_hi(u0.x), acc.y);
            acc.z = fmaf(w0, bf_lo(u0.y), acc.z); acc.w = fmaf(w0, bf_hi(u0.y), acc.w);
            acc.x = fmaf(w1, bf_lo(u1.x), acc.x); acc.y = fmaf(w1, bf_hi(u1.x), acc.y);
            acc.z = fmaf(w1, bf_lo(u1.y), acc.z); acc.w = fmaf(w1, bf_hi(u1.y), acc.w);
            acc.x = fmaf(w2, bf_lo(u2.x), acc.x); acc.y = fmaf(w2, bf_hi(u2.x), acc.y);
            acc.z = fmaf(w2, bf_lo(u2.y), acc.z); acc.w = fmaf(w2, bf_hi(u2.y), acc.w);
            acc.x = fmaf(w3, bf_lo(u3.x), acc.x); acc.y = fmaf(w3, bf_hi(u3.x), acc.y);
            acc.z = fmaf(w3, bf_lo(u3.y), acc.z); acc.w = fmaf(w3, bf_hi(u3.y), acc.w);
        }
        for (; k < deg; ++k) {
            const uint2 u = hp[(size_t)nbr[r][k] * 64 + lane];
            const float wk = wts[r][k][head];
            acc.x = fmaf(wk, bf_lo(u.x), acc.x); acc.y = fmaf(wk, bf_hi(u.x), acc.y);
            acc.z = fmaf(wk, bf_lo(u.y), acc.z); acc.w = fmaf(wk, bf_hi(u.y), acc.w);
        }
        const float s = head == 0 ? sm.x : head == 1 ? sm.y : head == 2 ? sm.z : sm.w;
        inv = 1.f / s;
    }

    float4 o;
    o.x = acc.x * inv; o.y = acc.y * inv; o.z = acc.z * inv; o.w = acc.w * inv;
    *(float4*)(out + (size_t)i * (HH * DHH) + 4 * lane) = o;   // fp32 output
}

// ---------------------------------------------------------------------------
extern "C" void kernel_launch(void* const* d_in, const int* in_sizes, int n_in,
                              void* d_out, int out_size, void* d_ws, size_t ws_size,
                              hipStream_t stream)
{
    const float* x     = (const float*)d_in[0];
    const float* ev    = (const float*)d_in[1];
    // d_in[2..5] = W1,b1,W2,b2 (edge MLP) -- provably irrelevant to the output
    const float* W     = (const float*)d_in[6];
    const float* a_src = (const float*)d_in[7];
    const float* a_dst = (const float*)d_in[8];
    const int*   ei    = (const int*)d_in[9];
    float* out = (float*)d_out;

    char* ws = (char*)d_ws;
    bf16*  hb    = (bf16*)ws;                               // 2 MB
    float* esrc  = (float*)(ws + 2097152);                  // 64 KB
    float* edst  = (float*)(ws + 2162688);                  // 64 KB
    unsigned int* bmg = (unsigned int*)(ws + 2228224);      // 2 MB adj bitmask

    hipMemsetAsync(bmg, 0, NN * (NN / 32) * sizeof(unsigned int), stream);
    hproj_edges_kernel<<<NN / 16, 1024, 0, stream>>>(x, W, a_src, a_dst, ei, ev,
                                                     hb, esrc, edst, bmg);
    attn_kernel<<<NN / RPB, 128, 0, stream>>>(bmg, hb, esrc, edst, out);
}